// Round 1
// baseline (903.011 us; speedup 1.0000x reference)
//
#include <hip/hip_runtime.h>
#include <cstdint>
#include <cstddef>

// Problem constants (from reference): B=32, T=4096, 2H=1024, DFF=512
#define B_SZ 32
#define T_SZ 4096
#define H2   1024
#define DFF_ 512
#define TM   64           // t-rows per block
#define BK   32           // K per step
#define NSTEP (H2 / BK)   // 32
#define PAD  8
#define LDB  (BK + PAD)   // 40 shorts = 80 B row stride (2-way bank alias = free)

typedef __attribute__((ext_vector_type(8))) short bf16x8;
typedef __attribute__((ext_vector_type(4))) float f32x4;

__device__ __forceinline__ unsigned short f2bf(float x) {
  unsigned u = __float_as_uint(x);
  u += 0x7fffu + ((u >> 16) & 1u);   // RNE
  return (unsigned short)(u >> 16);
}

// Pack U_a_w [512][1024] fp32 -> Upk[ks][f][LDB] bf16, pad never read.
__global__ void prep_u_kernel(const float* __restrict__ U,
                              unsigned short* __restrict__ Upk) {
  int g = blockIdx.x * 256 + threadIdx.x;     // [0, 32*512*32)
  int k  = g & 31;
  int f  = (g >> 5) & 511;
  int ks = g >> 14;
  float v = U[f * H2 + ks * 32 + k];
  Upk[(ks * DFF_ + f) * LDB + k] = f2bf(v);
}

// ws[b][f] = s[b]·W[f] + Wb[f] + Ub[f]   (fp32, exact)
__global__ void prep_ws_kernel(const float* __restrict__ s, const float* __restrict__ W,
                               const float* __restrict__ Wb, const float* __restrict__ Ub,
                               float* __restrict__ wsm) {
  int idx = blockIdx.x * 256 + threadIdx.x;   // [0, 32*512)
  int b = idx >> 9, f = idx & 511;
  const float4* s4 = (const float4*)(s + b * 512);
  const float4* w4 = (const float4*)(W + f * 512);
  float acc = 0.f;
  #pragma unroll 4
  for (int i = 0; i < 128; ++i) {
    float4 a = s4[i], w = w4[i];
    acc += a.x * w.x + a.y * w.y + a.z * w.z + a.w * w.w;
  }
  wsm[idx] = acc + Wb[f] + Ub[f];
}

// Fused: uh GEMM (bf16 MFMA) + tanh + energy dot + context reduction.
// Block: 512 threads = 8 waves. Wave (r=wave&3, ch=wave>>2):
//   rows [r*16, r*16+16), cols [ch*256, ch*256+256) = 16 MFMA col-tiles.
__global__ __launch_bounds__(512) void attn_main(
    const float* __restrict__ h, const unsigned short* __restrict__ Upk,
    const float* __restrict__ wsm, const float* __restrict__ Vw,
    const float* __restrict__ Vb, float* __restrict__ out) {
  __shared__ unsigned short As[TM * LDB];     // 5120 B
  __shared__ unsigned short Bs[DFF_ * LDB];   // 40960 B
  __shared__ float ws_s[DFF_];
  __shared__ float V_s[DFF_];
  __shared__ float energy_s[TM];

  const int tid  = threadIdx.x;
  const int blk  = blockIdx.x;            // 2048 blocks
  const int b    = blk >> 6;              // 64 tiles per batch
  const int t0   = (blk & 63) * TM;
  const int lane = tid & 63;
  const int wave = tid >> 6;
  const int ln15 = lane & 15;
  const int q    = lane >> 4;
  const int r    = wave & 3;
  const int ch   = wave >> 2;

  ws_s[tid] = wsm[b * DFF_ + tid];
  V_s[tid]  = Vw[tid];
  if (tid < TM) energy_s[tid] = Vb[0];    // fold V_a_b into energy init

  f32x4 acc[16];
  #pragma unroll
  for (int i = 0; i < 16; ++i) acc[i] = (f32x4){0.f, 0.f, 0.f, 0.f};

  const int arow = tid >> 3;              // 0..63
  const int ac4  = (tid & 7) * 4;         // 0..28
  const float* hbase = h + ((size_t)(b * T_SZ + t0)) * H2;

  for (int ks = 0; ks < NSTEP; ++ks) {
    __syncthreads();   // previous compute done before LDS overwrite
    // --- A stage: h[t0+arow][ks*32+ac4 .. +4] fp32 -> bf16 ---
    float4 av = *(const float4*)(hbase + (size_t)arow * H2 + ks * 32 + ac4);
    ushort4 ab;
    ab.x = f2bf(av.x); ab.y = f2bf(av.y); ab.z = f2bf(av.z); ab.w = f2bf(av.w);
    *(ushort4*)&As[arow * LDB + ac4] = ab;
    // --- B stage: 40960 B contiguous copy, global_load_lds width=16 ---
    const char* gsrc = (const char*)(Upk + (size_t)ks * DFF_ * LDB);
    char* lbs = (char*)Bs;
    #pragma unroll
    for (int i = 0; i < 5; ++i) {
      int off = i * 8192 + tid * 16;      // wave-uniform base + lane*16 within each wave
      __builtin_amdgcn_global_load_lds(
        (const __attribute__((address_space(1))) unsigned int*)(gsrc + off),
        (__attribute__((address_space(3))) unsigned int*)(lbs + off),
        16, 0, 0);
    }
    __syncthreads();   // compiler drains vmcnt+lgkmcnt before barrier
    // --- MFMA: D[row][f] += A[row][e] * U[f][e] ---
    bf16x8 af = *(const bf16x8*)&As[(r * 16 + ln15) * LDB + q * 8];
    #pragma unroll
    for (int ct = 0; ct < 16; ++ct) {
      bf16x8 bfr = *(const bf16x8*)&Bs[(ch * 256 + ct * 16 + ln15) * LDB + q * 8];
      acc[ct] = __builtin_amdgcn_mfma_f32_16x16x32_bf16(af, bfr, acc[ct], 0, 0, 0);
    }
  }

  // --- epilogue: x = tanh(ws + uh); energy partial = x·V ---
  // C/D layout: col f = base + lane&15, row = r*16 + q*4 + reg  [m89/m91]
  float esum[4] = {0.f, 0.f, 0.f, 0.f};
  #pragma unroll
  for (int ct = 0; ct < 16; ++ct) {
    int f = ch * 256 + ct * 16 + ln15;
    float wsf = ws_s[f], vf = V_s[f];
    #pragma unroll
    for (int rg = 0; rg < 4; ++rg) {
      float z = wsf + acc[ct][rg];
      float e = __expf(2.f * z);          // tanh(z) = 1 - 2/(e^{2z}+1); saturates correctly
      float x = 1.f - 2.f / (e + 1.f);
      esum[rg] += x * vf;
    }
  }
  // reduce across the 16 lanes of each quad (low 4 lane bits only)
  #pragma unroll
  for (int rg = 0; rg < 4; ++rg) {
    #pragma unroll
    for (int m = 1; m < 16; m <<= 1) esum[rg] += __shfl_xor(esum[rg], m, 64);
  }
  if (ln15 == 0) {
    #pragma unroll
    for (int rg = 0; rg < 4; ++rg)
      atomicAdd(&energy_s[r * 16 + q * 4 + rg], esum[rg]);
  }
  __syncthreads();

  // --- context: out[b][e] += sum_row energy[row] * h[b][t0+row][e] ---
  int e0 = tid * 2;                       // 512 threads * 2 = 1024 cols
  float c0 = 0.f, c1 = 0.f;
  const float2* h2p = (const float2*)hbase + (e0 >> 1);
  #pragma unroll 4
  for (int row = 0; row < TM; ++row) {
    float en = energy_s[row];
    float2 hv = h2p[(size_t)row * (H2 / 2)];
    c0 += en * hv.x;
    c1 += en * hv.y;
  }
  atomicAdd(&out[b * H2 + e0], c0);
  atomicAdd(&out[b * H2 + e0 + 1], c1);
}

extern "C" void kernel_launch(void* const* d_in, const int* in_sizes, int n_in,
                              void* d_out, int out_size, void* d_ws, size_t ws_size,
                              hipStream_t stream) {
  const float* s  = (const float*)d_in[0];
  const float* h  = (const float*)d_in[1];
  const float* Ww = (const float*)d_in[2];
  const float* Wb = (const float*)d_in[3];
  const float* Uw = (const float*)d_in[4];
  const float* Ub = (const float*)d_in[5];
  const float* Vw = (const float*)d_in[6];
  const float* Vb = (const float*)d_in[7];
  float* out = (float*)d_out;

  unsigned short* Upk = (unsigned short*)d_ws;                    // 32*512*40*2 = 1,310,720 B
  float* wsm = (float*)((char*)d_ws + (size_t)NSTEP * DFF_ * LDB * 2);  // 64 KB

  hipMemsetAsync(out, 0, (size_t)out_size * sizeof(float), stream);
  prep_u_kernel<<<(NSTEP * DFF_ * BK) / 256, 256, 0, stream>>>(Uw, Upk);
  prep_ws_kernel<<<(B_SZ * DFF_) / 256, 256, 0, stream>>>(s, Ww, Wb, Ub, wsm);
  attn_main<<<B_SZ * (T_SZ / TM), 512, 0, stream>>>(h, Upk, wsm, Vw, Vb, out);
}

// Round 2
// 899.272 us; speedup vs baseline: 1.0042x; 1.0042x over previous
//
#include <hip/hip_runtime.h>
#include <cstdint>
#include <cstddef>

// Problem constants: B=32, T=4096, 2H=1024, DFF=512
#define B_SZ 32
#define T_SZ 4096
#define H2   1024
#define DFF_ 512
#define TM   64           // t-rows per block
#define BK   32           // K per step
#define NSTEP (H2 / BK)   // 32

typedef __attribute__((ext_vector_type(8))) short bf16x8;
typedef __attribute__((ext_vector_type(4))) float f32x4;

__device__ __forceinline__ unsigned short f2bf(float x) {
  unsigned u = __float_as_uint(x);
  u += 0x7fffu + ((u >> 16) & 1u);   // RNE
  return (unsigned short)(u >> 16);
}

// Pack U [512][1024] fp32 -> Upk in MFMA-fragment order:
// Upk[((ks*32 + ct)*64 + l)*8 + j] = bf16(U[ct*16 + (l&15)][ks*32 + (l>>4)*8 + j])
// => per K-step a contiguous 32KB image; every ds_read_b128 is a contiguous
//    1KB wave read (lane*16) => zero bank conflicts.
__global__ void prep_u_kernel(const float* __restrict__ U,
                              unsigned short* __restrict__ Upk) {
  int g = blockIdx.x * 256 + threadIdx.x;     // [0, 524288)
  int j  = g & 7;
  int l  = (g >> 3) & 63;
  int ct = (g >> 9) & 31;
  int ks = g >> 14;
  int f  = ct * 16 + (l & 15);
  int k  = ks * 32 + (l >> 4) * 8 + j;
  Upk[g] = f2bf(U[f * H2 + k]);
}

// ws[b][f] = s[b]·W[f] + Wb[f] + Ub[f]   (fp32, exact)
__global__ void prep_ws_kernel(const float* __restrict__ s, const float* __restrict__ W,
                               const float* __restrict__ Wb, const float* __restrict__ Ub,
                               float* __restrict__ wsm) {
  int idx = blockIdx.x * 256 + threadIdx.x;   // [0, 32*512)
  int b = idx >> 9, f = idx & 511;
  const float4* s4 = (const float4*)(s + b * 512);
  const float4* w4 = (const float4*)(W + f * 512);
  float acc = 0.f;
  #pragma unroll 4
  for (int i = 0; i < 128; ++i) {
    float4 a = s4[i], w = w4[i];
    acc += a.x * w.x + a.y * w.y + a.z * w.z + a.w * w.w;
  }
  wsm[idx] = acc + Wb[f] + Ub[f];
}

// Fused uh GEMM + tanh + energy + context.
// Block: 512 thr = 8 waves; wave w = col-group cg, tile 64 rows x 64 cols
// (16 MFMA acc tiles => 4 A + 4 B b128 reads per 16 MFMA = 0.5KB/MFMA).
__global__ __launch_bounds__(512, 4) void attn_main(
    const float* __restrict__ h, const unsigned short* __restrict__ Upk,
    const float* __restrict__ wsm, const float* __restrict__ Vw,
    const float* __restrict__ Vb, float* __restrict__ out) {
  __shared__ unsigned short Bs[2][NSTEP ? 32 * 64 * 8 : 1];  // 2 x 32KB
  __shared__ unsigned short As[2][4 * 64 * 8];               // 2 x 4KB
  __shared__ float ws_s[DFF_];
  __shared__ float V_s[DFF_];
  __shared__ float energy_part[8][TM];
  __shared__ float energy_s[TM];

  const int tid  = threadIdx.x;
  const int blk  = blockIdx.x;            // 2048 blocks
  const int b    = blk >> 6;
  const int t0   = (blk & 63) * TM;
  const int lane = tid & 63;
  const int cg   = tid >> 6;              // wave = col-group 0..7
  const int ln15 = lane & 15;
  const int q4   = lane >> 4;

  ws_s[tid] = wsm[b * DFF_ + tid];
  V_s[tid]  = Vw[tid];

  // A staging geometry: thread -> (row, 4 k-elems) -> fragment-order slot
  const int arow = tid >> 3;              // 0..63
  const int ak   = (tid & 7) * 4;         // 0,4,...,28
  const int a_off = (arow >> 4) * 512 + (ak >> 3) * 128 + (arow & 15) * 8 + (ak & 7);
  const float* hbase = h + ((size_t)(b * T_SZ + t0)) * H2;
  const float* aptr  = hbase + (size_t)arow * H2 + ak;

  f32x4 acc[16];
  #pragma unroll
  for (int i = 0; i < 16; ++i) acc[i] = (f32x4){0.f, 0.f, 0.f, 0.f};

  // --- staging lambdas ---
  auto stageB = [&](int ks, int buf) {
    const char* gsrc = (const char*)Upk + (size_t)ks * 32768;
    char* ldst = (char*)&Bs[buf][0];
    #pragma unroll
    for (int i = 0; i < 4; ++i) {
      int off = i * 8192 + tid * 16;      // wave-uniform base + lane*16
      __builtin_amdgcn_global_load_lds(
        (const __attribute__((address_space(1))) unsigned int*)(gsrc + off),
        (__attribute__((address_space(3))) unsigned int*)(ldst + off),
        16, 0, 0);
    }
  };
  auto writeA = [&](float4 av, int buf) {
    ushort4 ab;
    ab.x = f2bf(av.x); ab.y = f2bf(av.y); ab.z = f2bf(av.z); ab.w = f2bf(av.w);
    *(ushort4*)&As[buf][a_off] = ab;
  };

  // --- prologue: stage step 0 into buf 0 ---
  stageB(0, 0);
  {
    float4 av0 = *(const float4*)(aptr);
    writeA(av0, 0);
  }
  __syncthreads();

  // --- K loop: compute cur, prefetch nxt, one barrier per step ---
  for (int ks = 0; ks < NSTEP; ++ks) {
    const int cur = ks & 1;
    float4 av;
    if (ks < NSTEP - 1) {
      stageB(ks + 1, cur ^ 1);
      av = *(const float4*)(aptr + (ks + 1) * BK);
    }
    bf16x8 af[4];
    #pragma unroll
    for (int rt = 0; rt < 4; ++rt)
      af[rt] = *(const bf16x8*)&As[cur][rt * 512 + lane * 8];
    #pragma unroll
    for (int ct2 = 0; ct2 < 4; ++ct2) {
      int ct = cg * 4 + ct2;
      bf16x8 bfr = *(const bf16x8*)&Bs[cur][(ct * 64 + lane) * 8];
      #pragma unroll
      for (int rt = 0; rt < 4; ++rt)
        acc[ct2 * 4 + rt] =
          __builtin_amdgcn_mfma_f32_16x16x32_bf16(af[rt], bfr, acc[ct2 * 4 + rt], 0, 0, 0);
    }
    if (ks < NSTEP - 1) writeA(av, cur ^ 1);
    __syncthreads();
  }

  // --- epilogue: x = tanh(ws + uh); energy partial = x·V ---
  // C/D layout: col f = tilebase + ln15, row = rt*16 + q4*4 + rg
  float esum[16];
  #pragma unroll
  for (int i = 0; i < 16; ++i) esum[i] = 0.f;
  #pragma unroll
  for (int ct2 = 0; ct2 < 4; ++ct2) {
    int f = cg * 64 + ct2 * 16 + ln15;
    float wsf = ws_s[f], vf = V_s[f];
    #pragma unroll
    for (int rt = 0; rt < 4; ++rt) {
      #pragma unroll
      for (int rg = 0; rg < 4; ++rg) {
        float z = wsf + acc[ct2 * 4 + rt][rg];
        float e = __expf(2.f * z);
        float x = 1.f - 2.f / (e + 1.f);
        esum[rt * 4 + rg] += x * vf;
      }
    }
  }
  #pragma unroll
  for (int i = 0; i < 16; ++i) {
    #pragma unroll
    for (int m = 1; m < 16; m <<= 1) esum[i] += __shfl_xor(esum[i], m, 64);
  }
  if (ln15 == 0) {
    #pragma unroll
    for (int rt = 0; rt < 4; ++rt)
      #pragma unroll
      for (int rg = 0; rg < 4; ++rg)
        energy_part[cg][rt * 16 + q4 * 4 + rg] = esum[rt * 4 + rg];
  }
  __syncthreads();
  if (tid < TM) {
    float e = Vb[0];
    #pragma unroll
    for (int w = 0; w < 8; ++w) e += energy_part[w][tid];
    energy_s[tid] = e;
  }
  __syncthreads();

  // --- context: out[b][e] += sum_row energy[row] * h[row][e] (L2/L3-hot) ---
  int e0 = tid * 2;
  float c0 = 0.f, c1 = 0.f;
  const float2* h2p = (const float2*)hbase + (e0 >> 1);
  #pragma unroll 4
  for (int row = 0; row < TM; ++row) {
    float en = energy_s[row];
    float2 hv = h2p[(size_t)row * (H2 / 2)];
    c0 += en * hv.x;
    c1 += en * hv.y;
  }
  atomicAdd(&out[b * H2 + e0], c0);
  atomicAdd(&out[b * H2 + e0 + 1], c1);
}

extern "C" void kernel_launch(void* const* d_in, const int* in_sizes, int n_in,
                              void* d_out, int out_size, void* d_ws, size_t ws_size,
                              hipStream_t stream) {
  const float* s  = (const float*)d_in[0];
  const float* h  = (const float*)d_in[1];
  const float* Ww = (const float*)d_in[2];
  const float* Wb = (const float*)d_in[3];
  const float* Uw = (const float*)d_in[4];
  const float* Ub = (const float*)d_in[5];
  const float* Vw = (const float*)d_in[6];
  const float* Vb = (const float*)d_in[7];
  float* out = (float*)d_out;

  unsigned short* Upk = (unsigned short*)d_ws;                    // 1 MB
  float* wsm = (float*)((char*)d_ws + (size_t)NSTEP * 32768);     // 64 KB

  hipMemsetAsync(out, 0, (size_t)out_size * sizeof(float), stream);
  prep_u_kernel<<<(DFF_ * H2) / 256, 256, 0, stream>>>(Uw, Upk);
  prep_ws_kernel<<<(B_SZ * DFF_) / 256, 256, 0, stream>>>(s, Ww, Wb, Ub, wsm);
  attn_main<<<B_SZ * (T_SZ / TM), 512, 0, stream>>>(h, Upk, wsm, Vw, Vb, out);
}

// Round 3
// 886.650 us; speedup vs baseline: 1.0185x; 1.0142x over previous
//
#include <hip/hip_runtime.h>
#include <cstdint>
#include <cstddef>

// Problem constants: B=32, T=4096, 2H=1024, DFF=512
#define B_SZ 32
#define T_SZ 4096
#define H2   1024
#define DFF_ 512
#define TM   64           // t-rows per block
#define BK   32           // K per MFMA step
#define SPH  16           // steps per K-half
#define NSTEP 32

typedef __attribute__((ext_vector_type(8))) short bf16x8;
typedef __attribute__((ext_vector_type(4))) float f32x4;

__device__ __forceinline__ unsigned short f2bf(float x) {
  unsigned u = __float_as_uint(x);
  u += 0x7fffu + ((u >> 16) & 1u);   // RNE
  return (unsigned short)(u >> 16);
}

// Pack U [512][1024] fp32 -> Upk in MFMA-fragment order:
// Upk[((ks*32 + ct)*64 + l)*8 + j] = bf16(U[ct*16 + (l&15)][ks*32 + (l>>4)*8 + j])
// A wave's 4 B-fragments for (ks, col-group cg) are 4 contiguous 1KB reads.
__global__ void prep_u_kernel(const float* __restrict__ U,
                              unsigned short* __restrict__ Upk) {
  int g = blockIdx.x * 256 + threadIdx.x;     // [0, 524288)
  int j  = g & 7;
  int l  = (g >> 3) & 63;
  int ct = (g >> 9) & 31;
  int ks = g >> 14;
  int f  = ct * 16 + (l & 15);
  int k  = ks * 32 + (l >> 4) * 8 + j;
  Upk[g] = f2bf(U[f * H2 + k]);
}

// ws[b][f] = s[b]·W[f] + Wb[f] + Ub[f]   (fp32, exact)
__global__ void prep_ws_kernel(const float* __restrict__ s, const float* __restrict__ W,
                               const float* __restrict__ Wb, const float* __restrict__ Ub,
                               float* __restrict__ wsm) {
  int idx = blockIdx.x * 256 + threadIdx.x;   // [0, 32*512)
  int b = idx >> 9, f = idx & 511;
  const float4* s4 = (const float4*)(s + b * 512);
  const float4* w4 = (const float4*)(W + f * 512);
  float acc = 0.f;
  #pragma unroll 4
  for (int i = 0; i < 128; ++i) {
    float4 a = s4[i], w = w4[i];
    acc += a.x * w.x + a.y * w.y + a.z * w.z + a.w * w.w;
  }
  wsm[idx] = acc + Wb[f] + Ub[f];
}

// Fused uh GEMM + tanh + energy + context, barrier-free K-loop:
//  - B fragments: global->register loads from L2-hot Upk, depth-1 prefetch.
//  - A tile: staged per K-half into 64KB LDS (3 barriers/block total).
// Block: 512 thr = 8 waves; wave = col-group (64 cols), 64 rows, 16 acc tiles.
__global__ __launch_bounds__(512, 4) void attn_main(
    const float* __restrict__ h, const unsigned short* __restrict__ Upk,
    const float* __restrict__ wsm, const float* __restrict__ Vw,
    const float* __restrict__ Vb, float* __restrict__ out) {
  __shared__ unsigned short As[SPH * 2048];   // 64 KB: [step][rt*512 + lane*8 + j]
  __shared__ float ws_s[DFF_];
  __shared__ float V_s[DFF_];
  __shared__ float energy_part[8][TM];
  __shared__ float energy_s[TM];

  const int tid  = threadIdx.x;
  const int blk  = blockIdx.x;            // 2048 blocks
  const int b    = blk >> 6;
  const int t0   = (blk & 63) * TM;
  const int lane = tid & 63;
  const int cg   = tid >> 6;              // wave = col-group 0..7
  const int ln15 = lane & 15;
  const int q4   = lane >> 4;

  ws_s[tid] = wsm[b * DFF_ + tid];
  V_s[tid]  = Vw[tid];

  // A staging geometry: thread -> (row, 4 k-elems) -> fragment-order slot
  const int arow = tid >> 3;              // 0..63
  const int ak   = (tid & 7) * 4;         // 0,4,...,28
  const int a_off = (arow >> 4) * 512 + (ak >> 3) * 128 + (arow & 15) * 8 + (ak & 7);
  const float* hbase = h + ((size_t)(b * T_SZ + t0)) * H2;
  const float* hrow  = hbase + (size_t)arow * H2 + ak;

  const bf16x8* Upk8 = (const bf16x8*)Upk;  // fragment index = (ks*32+ct)*64 + lane

  f32x4 acc[16];
  #pragma unroll
  for (int i = 0; i < 16; ++i) acc[i] = (f32x4){0.f, 0.f, 0.f, 0.f};

  for (int hk = 0; hk < 2; ++hk) {
    if (hk) __syncthreads();              // compute of prev half done before overwrite
    // ---- stage A for this K-half: 16 steps x 4KB, 8 loads in flight ----
    {
      float4 avv[8];
      #pragma unroll
      for (int j = 0; j < 8; ++j) avv[j] = *(const float4*)(hrow + hk * 512 + j * BK);
      #pragma unroll
      for (int j = 0; j < 8; ++j) {
        ushort4 ab;
        ab.x = f2bf(avv[j].x); ab.y = f2bf(avv[j].y);
        ab.z = f2bf(avv[j].z); ab.w = f2bf(avv[j].w);
        *(ushort4*)&As[j * 2048 + a_off] = ab;
      }
      #pragma unroll
      for (int j = 0; j < 8; ++j) avv[j] = *(const float4*)(hrow + hk * 512 + (j + 8) * BK);
      #pragma unroll
      for (int j = 0; j < 8; ++j) {
        ushort4 ab;
        ab.x = f2bf(avv[j].x); ab.y = f2bf(avv[j].y);
        ab.z = f2bf(avv[j].z); ab.w = f2bf(avv[j].w);
        *(ushort4*)&As[(j + 8) * 2048 + a_off] = ab;
      }
    }
    __syncthreads();
    // ---- 16 barrier-free K-steps; B depth-1 register prefetch from L2 ----
    const int ksbase = hk * SPH;
    bf16x8 bcur[4], bnxt[4];
    {
      size_t base = ((size_t)(ksbase * 32 + cg * 4)) * 64 + lane;
      #pragma unroll
      for (int i = 0; i < 4; ++i) bcur[i] = Upk8[base + (size_t)i * 64];
    }
    #pragma unroll
    for (int s = 0; s < SPH; ++s) {
      if (s < SPH - 1) {
        size_t base = ((size_t)((ksbase + s + 1) * 32 + cg * 4)) * 64 + lane;
        #pragma unroll
        for (int i = 0; i < 4; ++i) bnxt[i] = Upk8[base + (size_t)i * 64];
      }
      bf16x8 af[4];
      #pragma unroll
      for (int rt = 0; rt < 4; ++rt)
        af[rt] = *(const bf16x8*)&As[s * 2048 + rt * 512 + lane * 8];
      #pragma unroll
      for (int ct2 = 0; ct2 < 4; ++ct2)
        #pragma unroll
        for (int rt = 0; rt < 4; ++rt)
          acc[ct2 * 4 + rt] =
            __builtin_amdgcn_mfma_f32_16x16x32_bf16(af[rt], bcur[ct2], acc[ct2 * 4 + rt], 0, 0, 0);
      #pragma unroll
      for (int i = 0; i < 4; ++i) bcur[i] = bnxt[i];
    }
  }

  // --- epilogue: x = tanh(ws + uh); energy partial = x·V ---
  // C/D layout: col f = tilebase + ln15, row = rt*16 + q4*4 + rg
  float esum[16];
  #pragma unroll
  for (int i = 0; i < 16; ++i) esum[i] = 0.f;
  #pragma unroll
  for (int ct2 = 0; ct2 < 4; ++ct2) {
    int f = cg * 64 + ct2 * 16 + ln15;
    float wsf = ws_s[f], vf = V_s[f];
    #pragma unroll
    for (int rt = 0; rt < 4; ++rt) {
      #pragma unroll
      for (int rg = 0; rg < 4; ++rg) {
        float z = wsf + acc[ct2 * 4 + rt][rg];
        float e = __expf(2.f * z);
        float x = 1.f - 2.f / (e + 1.f);
        esum[rt * 4 + rg] += x * vf;
      }
    }
  }
  #pragma unroll
  for (int i = 0; i < 16; ++i) {
    #pragma unroll
    for (int m = 1; m < 16; m <<= 1) esum[i] += __shfl_xor(esum[i], m, 64);
  }
  if (ln15 == 0) {
    #pragma unroll
    for (int rt = 0; rt < 4; ++rt)
      #pragma unroll
      for (int rg = 0; rg < 4; ++rg)
        energy_part[cg][rt * 16 + q4 * 4 + rg] = esum[rt * 4 + rg];
  }
  __syncthreads();
  if (tid < TM) {
    float e = Vb[0];
    #pragma unroll
    for (int w = 0; w < 8; ++w) e += energy_part[w][tid];
    energy_s[tid] = e;
  }
  __syncthreads();

  // --- context: out[b][e] += sum_row energy[row] * h[row][e] (L2-hot) ---
  int e0 = tid * 2;
  float c0 = 0.f, c1 = 0.f;
  const float2* h2p = (const float2*)hbase + (e0 >> 1);
  #pragma unroll 4
  for (int row = 0; row < TM; ++row) {
    float en = energy_s[row];
    float2 hv = h2p[(size_t)row * (H2 / 2)];
    c0 += en * hv.x;
    c1 += en * hv.y;
  }
  atomicAdd(&out[b * H2 + e0], c0);
  atomicAdd(&out[b * H2 + e0 + 1], c1);
}

extern "C" void kernel_launch(void* const* d_in, const int* in_sizes, int n_in,
                              void* d_out, int out_size, void* d_ws, size_t ws_size,
                              hipStream_t stream) {
  const float* s  = (const float*)d_in[0];
  const float* h  = (const float*)d_in[1];
  const float* Ww = (const float*)d_in[2];
  const float* Wb = (const float*)d_in[3];
  const float* Uw = (const float*)d_in[4];
  const float* Ub = (const float*)d_in[5];
  const float* Vw = (const float*)d_in[6];
  const float* Vb = (const float*)d_in[7];
  float* out = (float*)d_out;

  unsigned short* Upk = (unsigned short*)d_ws;                    // 1 MB
  float* wsm = (float*)((char*)d_ws + (size_t)NSTEP * 32768);     // 64 KB

  hipMemsetAsync(out, 0, (size_t)out_size * sizeof(float), stream);
  prep_u_kernel<<<(DFF_ * H2) / 256, 256, 0, stream>>>(Uw, Upk);
  prep_ws_kernel<<<(B_SZ * DFF_) / 256, 256, 0, stream>>>(s, Ww, Wb, Ub, wsm);
  attn_main<<<B_SZ * (T_SZ / TM), 512, 0, stream>>>(h, Upk, wsm, Vw, Vb, out);
}